// Round 2
// baseline (2053.764 us; speedup 1.0000x reference)
//
#include <hip/hip_runtime.h>
#include <stdint.h>

// ---------------------------------------------------------------------------
// GraphAggregator: fused 3-layer MLP (256->512->512->128) + SiLU + segment-sum
// Round 2: BM=128 rows/block, 512 threads (8 waves), dynamic LDS 160 KiB.
//  - h1/h2 (128x512 bf16 = 128 KB) live in LDS region HX; h2 overwrites h1
//    in place (acc stays in registers across the barrier).
//  - X staged in two 32 KB K-halves into XS (HX 128K + XS 32K = 160 KiB).
//  - Column-split waves: each of 512 weight columns owned by exactly one
//    wave -> every packed B-fragment is fetched from L2 ONCE per block.
//    Weight L2 traffic: 897 KB x 3907 blocks = 3.5 GB (~100 us) < MFMA floor.
//  - Swizzle swz(m)=(m^(m>>3))&7 on 16B granules: A-frag ds_read_b128 2-way
//    (free), epilogue bf16 stores 2-way (was 4-way with m&7).
// ---------------------------------------------------------------------------

typedef short bf16x8 __attribute__((ext_vector_type(8)));   // 8 bf16 = 4 VGPRs
typedef float f32x4  __attribute__((ext_vector_type(4)));

#define N_NODES   500000
#define BM        128
#define N_BLOCKS  ((N_NODES + BM - 1) / BM)   // 3907 (last block: 32 rows)
#define N_GRAPHS  1024
#define N_OUT     128

#define HX_BYTES  131072                      // 128 rows x 1024 B (bf16 x 512)
#define LDS_BYTES (HX_BYTES + 32768)          // + X-half staging = 163840

// packed-weight offsets in bf16 elements inside d_ws
#define W1P_ELEMS (256*512)
#define W2P_ELEMS (512*512)
#define W3P_ELEMS (512*128)
#define W2P_OFF   (W1P_ELEMS)
#define W3P_OFF   (W1P_ELEMS + W2P_ELEMS)
#define PREPACK_THREADS ((W1P_ELEMS + W2P_ELEMS + W3P_ELEMS) / 8)  // 57344

__device__ __forceinline__ short f2bf(float x) {
    uint32_t u = __float_as_uint(x);
    u += 0x7fffu + ((u >> 16) & 1u);
    return (short)(u >> 16);
}
__device__ __forceinline__ int swz(int m) { return (m ^ (m >> 3)) & 7; }

// Pack W[K][N] (row-major fp32) into per-(ntile,ktile) MFMA B fragments:
// dst[((nt*Ktiles + kt)*64 + lane)*8 + j] = bf16( W[kt*32+(lane>>4)*8+j][nt*16+(lane&15)] )
__global__ void prepack_weights(const float* __restrict__ W1,
                                const float* __restrict__ W2,
                                const float* __restrict__ W3,
                                short* __restrict__ wp) {
    int tid = blockIdx.x * blockDim.x + threadIdx.x;
    if (tid >= PREPACK_THREADS) return;
    const float* src; int N, kmask, kshift, dstoff, local;
    if (tid < 16384) {              // W1: K=256 (8 ktiles), N=512
        src = W1; N = 512; kmask = 7;  kshift = 3; dstoff = 0;       local = tid;
    } else if (tid < 49152) {       // W2: K=512 (16 ktiles), N=512
        src = W2; N = 512; kmask = 15; kshift = 4; dstoff = W2P_OFF; local = tid - 16384;
    } else {                        // W3: K=512 (16 ktiles), N=128
        src = W3; N = 128; kmask = 15; kshift = 4; dstoff = W3P_OFF; local = tid - 49152;
    }
    const int lane = local & 63;
    const int tile = local >> 6;
    const int kt = tile & kmask;
    const int nt = tile >> kshift;
    const int k0 = kt * 32 + (lane >> 4) * 8;
    const int n  = nt * 16 + (lane & 15);
    const float* s = src + (size_t)k0 * N + n;
    union { bf16x8 v; short e[8]; } u;
#pragma unroll
    for (int j = 0; j < 8; ++j) u.e[j] = f2bf(s[(size_t)j * N]);
    *((bf16x8*)(wp + dstoff) + local) = u.v;
}

__launch_bounds__(512, 2)
__global__ void fused_mlp(const float* __restrict__ X,
                          const int*   __restrict__ gidx,
                          const short* __restrict__ wp,
                          const float* __restrict__ b1,
                          const float* __restrict__ b2,
                          const float* __restrict__ b3,
                          float* __restrict__ out) {
    extern __shared__ char lds[];
    char* HX = lds;                 // h1 / h2 (bf16, 1024 B/row) then y (f32)
    char* XS = lds + HX_BYTES;      // X K-half staging (bf16, 256 B/row); later gs

    const int t    = threadIdx.x;
    const int lane = t & 63;
    const int wave = t >> 6;        // 0..7
    const int q    = lane >> 4;
    const int l15  = lane & 15;
    const int64_t rowBase = (int64_t)blockIdx.x * BM;
    const int valid = (int)min((int64_t)BM, (int64_t)N_NODES - rowBase);

    const f32x4 zero4 = {0.f, 0.f, 0.f, 0.f};
    f32x4 acc[8][4];                // [row-tile][col-tile-local], 128 regs

    // =============== Phase 1: h1 = relu(X @ W1 + b1), K=256 ================
#pragma unroll
    for (int rt = 0; rt < 8; ++rt)
#pragma unroll
        for (int c = 0; c < 4; ++c) acc[rt][c] = zero4;

    const bf16x8* w1 = (const bf16x8*)wp;
    for (int half = 0; half < 2; ++half) {
        if (half) __syncthreads();              // prev MFMA reads of XS done
        // ---- stage X half: 128 rows x 128 fp32 -> bf16 swizzled (256 B/row)
        {
            int m  = t >> 5;                    // 0..15, step 16
            const int ch = t & 31;              // float4 chunk in half-row
            const int g   = ch >> 1;            // 16B granule (2 chunks each)
            const int sel = ch & 1;
#pragma unroll
            for (int p = 0; p < 8; ++p, m += 16) {
                float4 f = {0.f, 0.f, 0.f, 0.f};
                if (m < valid)
                    f = *(const float4*)(X + (rowBase + m) * 256 + half * 128 + ch * 4);
                short4 h4;
                h4.x = f2bf(f.x); h4.y = f2bf(f.y); h4.z = f2bf(f.z); h4.w = f2bf(f.w);
                *(short4*)(XS + m * 256 + ((g ^ swz(m)) << 4) + sel * 8) = h4;
            }
        }
        __syncthreads();
        // ---- MFMA over 4 ktiles of this half
        for (int ktl = 0; ktl < 4; ++ktl) {
            bf16x8 a[8];
#pragma unroll
            for (int rt = 0; rt < 8; ++rt) {
                const int m = rt * 16 + l15;
                const int g = ktl * 4 + q;      // granule 0..15
                a[rt] = *(const bf16x8*)(XS + m * 256 + ((g ^ swz(m)) << 4));
            }
#pragma unroll
            for (int c = 0; c < 4; ++c) {
                const int nt = wave * 4 + c;
                const bf16x8 b = w1[(nt * 8 + half * 4 + ktl) * 64 + lane];
#pragma unroll
                for (int rt = 0; rt < 8; ++rt)
                    acc[rt][c] = __builtin_amdgcn_mfma_f32_16x16x32_bf16(a[rt], b, acc[rt][c], 0, 0, 0);
            }
        }
    }
    // ---- epilogue: relu + bias -> HX (bf16, swizzled). HX first touch here.
#pragma unroll
    for (int c = 0; c < 4; ++c) {
        const int n = (wave * 4 + c) * 16 + l15;
        const float bias = b1[n];
        const int cg = n >> 3;
        const int nl = n & 7;
#pragma unroll
        for (int rt = 0; rt < 8; ++rt)
#pragma unroll
            for (int r = 0; r < 4; ++r) {
                const int m = rt * 16 + q * 4 + r;
                float v = acc[rt][c][r] + bias;
                v = fmaxf(v, 0.f);
                *(short*)(HX + m * 1024 + ((cg ^ swz(m)) << 4) + nl * 2) = f2bf(v);
            }
    }
    __syncthreads();

    // =============== Phase 2: h2 = relu(h1 @ W2 + b2), K=512 ===============
#pragma unroll
    for (int rt = 0; rt < 8; ++rt)
#pragma unroll
        for (int c = 0; c < 4; ++c) acc[rt][c] = zero4;

    const bf16x8* w2 = (const bf16x8*)wp + (W2P_OFF >> 3);
    for (int kt = 0; kt < 16; ++kt) {
        bf16x8 a[8];
#pragma unroll
        for (int rt = 0; rt < 8; ++rt) {
            const int m = rt * 16 + l15;
            const int g = kt * 4 + q;           // granule 0..63
            a[rt] = *(const bf16x8*)(HX + m * 1024 + ((g ^ swz(m)) << 4));
        }
#pragma unroll
        for (int c = 0; c < 4; ++c) {
            const int nt = wave * 4 + c;
            const bf16x8 b = w2[(nt * 16 + kt) * 64 + lane];
#pragma unroll
            for (int rt = 0; rt < 8; ++rt)
                acc[rt][c] = __builtin_amdgcn_mfma_f32_16x16x32_bf16(a[rt], b, acc[rt][c], 0, 0, 0);
        }
    }
    __syncthreads();                            // all h1 reads done
    // ---- epilogue: relu + bias -> HX in place (h2 overwrites h1)
#pragma unroll
    for (int c = 0; c < 4; ++c) {
        const int n = (wave * 4 + c) * 16 + l15;
        const float bias = b2[n];
        const int cg = n >> 3;
        const int nl = n & 7;
#pragma unroll
        for (int rt = 0; rt < 8; ++rt)
#pragma unroll
            for (int r = 0; r < 4; ++r) {
                const int m = rt * 16 + q * 4 + r;
                float v = acc[rt][c][r] + bias;
                v = fmaxf(v, 0.f);
                *(short*)(HX + m * 1024 + ((cg ^ swz(m)) << 4) + nl * 2) = f2bf(v);
            }
    }
    __syncthreads();

    // =============== Phase 3: y = silu(h2 @ W3 + b3), K=512 ================
    f32x4 acc3[8];
#pragma unroll
    for (int rt = 0; rt < 8; ++rt) acc3[rt] = zero4;

    const bf16x8* w3 = (const bf16x8*)wp + (W3P_OFF >> 3);
    for (int kt = 0; kt < 16; ++kt) {
        bf16x8 a[8];
#pragma unroll
        for (int rt = 0; rt < 8; ++rt) {
            const int m = rt * 16 + l15;
            const int g = kt * 4 + q;
            a[rt] = *(const bf16x8*)(HX + m * 1024 + ((g ^ swz(m)) << 4));
        }
        const bf16x8 b = w3[(wave * 16 + kt) * 64 + lane];
#pragma unroll
        for (int rt = 0; rt < 8; ++rt)
            acc3[rt] = __builtin_amdgcn_mfma_f32_16x16x32_bf16(a[rt], b, acc3[rt], 0, 0, 0);
    }
    __syncthreads();                            // all h2 reads done
    // ---- epilogue: silu -> y (f32, stride 132 floats) into HX; gs into XS
    {
        float* yl = (float*)HX;
        const int n = wave * 16 + l15;
        const float bias = b3[n];
#pragma unroll
        for (int rt = 0; rt < 8; ++rt)
#pragma unroll
            for (int r = 0; r < 4; ++r) {
                const int m = rt * 16 + q * 4 + r;
                const float yv = acc3[rt][r] + bias;
                yl[m * 132 + n] = yv / (1.f + __expf(-yv));   // SiLU
            }
        int* gs = (int*)XS;
        if (t < BM) gs[t] = (t < valid) ? gidx[rowBase + t] : 0;
    }
    __syncthreads();

    // =============== Phase 4: segmented reduction + global atomics =========
    {
        const int col = t & 127;
        const int r0  = (t >> 7) * 32;          // 4 row chunks of 32
        const int r1  = min(r0 + 32, valid);
        if (r0 < valid) {
            const int*   gs = (const int*)XS;
            const float* yl = (const float*)HX;
            int   gprev = gs[r0];
            float s     = 0.f;
            for (int r = r0; r < r1; ++r) {
                const int g = gs[r];
                if (g != gprev) {
                    atomicAdd(out + gprev * N_OUT + col, s);
                    s = 0.f;
                    gprev = g;
                }
                s += yl[r * 132 + col];
            }
            atomicAdd(out + gprev * N_OUT + col, s);
        }
    }
}

extern "C" void kernel_launch(void* const* d_in, const int* in_sizes, int n_in,
                              void* d_out, int out_size, void* d_ws, size_t ws_size,
                              hipStream_t stream) {
    const float* X    = (const float*)d_in[0];
    const int*   gidx = (const int*)  d_in[1];
    const float* W1   = (const float*)d_in[2];
    const float* b1   = (const float*)d_in[3];
    const float* W2   = (const float*)d_in[4];
    const float* b2   = (const float*)d_in[5];
    const float* W3   = (const float*)d_in[6];
    const float* b3   = (const float*)d_in[7];
    float* out = (float*)d_out;
    short* wp  = (short*)d_ws;

    // opt-in to >64 KiB dynamic LDS (idempotent, host-side, graph-safe)
    hipFuncSetAttribute((const void*)fused_mlp,
                        hipFuncAttributeMaxDynamicSharedMemorySize, LDS_BYTES);

    hipMemsetAsync(d_out, 0, sizeof(float) * N_GRAPHS * N_OUT, stream);

    prepack_weights<<<PREPACK_THREADS / 256, 256, 0, stream>>>(W1, W2, W3, wp);

    fused_mlp<<<N_BLOCKS, 512, LDS_BYTES, stream>>>(X, gidx, wp, b1, b2, b3, out);
}

// Round 3
// 2049.068 us; speedup vs baseline: 1.0023x; 1.0023x over previous
//
#include <hip/hip_runtime.h>
#include <stdint.h>

// ---------------------------------------------------------------------------
// GraphAggregator: fused 3-layer MLP (256->512->512->128) + SiLU + segment-sum
// Round 3 = Round 2 structure + fixed register budget.
//   Round 2 failed because __launch_bounds__(512,2) capped VGPRs at 128 while
//   acc[8][4] alone needs 128 -> full accumulator spill (WRITE_SIZE 1.2 GB).
//   __launch_bounds__(512,1) lets the allocator use 256 VGPRs (2 waves/SIMD,
//   block-fit) -> no spill.
// Structure: BM=128 rows/block, 512 threads (8 waves), dynamic LDS 160 KiB.
//   - h1/h2 (128x512 bf16 = 128 KB) in LDS region HX, h2 overwrites h1.
//   - X staged in two 32 KB K-halves into XS (128K + 32K = 160 KiB).
//   - Column-split waves: each packed B-fragment fetched from L2 once/block.
//     Weight L2 traffic: 897 KB x 3907 = 3.5 GB (~100 us) < MFMA floor 193 us.
// ---------------------------------------------------------------------------

typedef short bf16x8 __attribute__((ext_vector_type(8)));   // 8 bf16 = 4 VGPRs
typedef float f32x4  __attribute__((ext_vector_type(4)));

#define N_NODES   500000
#define BM        128
#define N_BLOCKS  ((N_NODES + BM - 1) / BM)   // 3907 (last block: 32 rows)
#define N_GRAPHS  1024
#define N_OUT     128

#define HX_BYTES  131072                      // 128 rows x 1024 B (bf16 x 512)
#define LDS_BYTES (HX_BYTES + 32768)          // + X-half staging = 163840

// packed-weight offsets in bf16 elements inside d_ws
#define W1P_ELEMS (256*512)
#define W2P_ELEMS (512*512)
#define W3P_ELEMS (512*128)
#define W2P_OFF   (W1P_ELEMS)
#define W3P_OFF   (W1P_ELEMS + W2P_ELEMS)
#define PREPACK_THREADS ((W1P_ELEMS + W2P_ELEMS + W3P_ELEMS) / 8)  // 57344

__device__ __forceinline__ short f2bf(float x) {
    uint32_t u = __float_as_uint(x);
    u += 0x7fffu + ((u >> 16) & 1u);
    return (short)(u >> 16);
}
__device__ __forceinline__ int swz(int m) { return (m ^ (m >> 3)) & 7; }

// Pack W[K][N] (row-major fp32) into per-(ntile,ktile) MFMA B fragments:
// dst[((nt*Ktiles + kt)*64 + lane)*8 + j] = bf16( W[kt*32+(lane>>4)*8+j][nt*16+(lane&15)] )
__global__ void prepack_weights(const float* __restrict__ W1,
                                const float* __restrict__ W2,
                                const float* __restrict__ W3,
                                short* __restrict__ wp) {
    int tid = blockIdx.x * blockDim.x + threadIdx.x;
    if (tid >= PREPACK_THREADS) return;
    const float* src; int N, kmask, kshift, dstoff, local;
    if (tid < 16384) {              // W1: K=256 (8 ktiles), N=512
        src = W1; N = 512; kmask = 7;  kshift = 3; dstoff = 0;       local = tid;
    } else if (tid < 49152) {       // W2: K=512 (16 ktiles), N=512
        src = W2; N = 512; kmask = 15; kshift = 4; dstoff = W2P_OFF; local = tid - 16384;
    } else {                        // W3: K=512 (16 ktiles), N=128
        src = W3; N = 128; kmask = 15; kshift = 4; dstoff = W3P_OFF; local = tid - 49152;
    }
    const int lane = local & 63;
    const int tile = local >> 6;
    const int kt = tile & kmask;
    const int nt = tile >> kshift;
    const int k0 = kt * 32 + (lane >> 4) * 8;
    const int n  = nt * 16 + (lane & 15);
    const float* s = src + (size_t)k0 * N + n;
    union { bf16x8 v; short e[8]; } u;
#pragma unroll
    for (int j = 0; j < 8; ++j) u.e[j] = f2bf(s[(size_t)j * N]);
    *((bf16x8*)(wp + dstoff) + local) = u.v;
}

__launch_bounds__(512, 1)   // 1 wave/EU min -> VGPR cap 256 (block-fit), NO SPILL
__global__ void fused_mlp(const float* __restrict__ X,
                          const int*   __restrict__ gidx,
                          const short* __restrict__ wp,
                          const float* __restrict__ b1,
                          const float* __restrict__ b2,
                          const float* __restrict__ b3,
                          float* __restrict__ out) {
    extern __shared__ char lds[];
    char* HX = lds;                 // h1 / h2 (bf16, 1024 B/row) then y (f32)
    char* XS = lds + HX_BYTES;      // X K-half staging (bf16, 256 B/row); later gs

    const int t    = threadIdx.x;
    const int lane = t & 63;
    const int wave = t >> 6;        // 0..7
    const int q    = lane >> 4;
    const int l15  = lane & 15;
    const int64_t rowBase = (int64_t)blockIdx.x * BM;
    const int valid = (int)min((int64_t)BM, (int64_t)N_NODES - rowBase);

    const f32x4 zero4 = {0.f, 0.f, 0.f, 0.f};
    f32x4 acc[8][4];                // [row-tile][col-tile-local], 128 VGPRs

    // =============== Phase 1: h1 = relu(X @ W1 + b1), K=256 ================
#pragma unroll
    for (int rt = 0; rt < 8; ++rt)
#pragma unroll
        for (int c = 0; c < 4; ++c) acc[rt][c] = zero4;

    const bf16x8* w1 = (const bf16x8*)wp;
    for (int half = 0; half < 2; ++half) {
        if (half) __syncthreads();              // prev MFMA reads of XS done
        // ---- stage X half: 128 rows x 128 fp32 -> bf16 swizzled (256 B/row)
        {
            int m  = t >> 5;                    // 0..15, step 16
            const int ch = t & 31;              // float4 chunk in half-row
            const int g   = ch >> 1;            // 16B granule (2 chunks each)
            const int sel = ch & 1;
#pragma unroll
            for (int p = 0; p < 8; ++p, m += 16) {
                float4 f = {0.f, 0.f, 0.f, 0.f};
                if (m < valid)
                    f = *(const float4*)(X + (rowBase + m) * 256 + half * 128 + ch * 4);
                short4 h4;
                h4.x = f2bf(f.x); h4.y = f2bf(f.y); h4.z = f2bf(f.z); h4.w = f2bf(f.w);
                *(short4*)(XS + m * 256 + ((g ^ swz(m)) << 4) + sel * 8) = h4;
            }
        }
        __syncthreads();
        // ---- MFMA over 4 ktiles of this half
        for (int ktl = 0; ktl < 4; ++ktl) {
            bf16x8 a[8];
#pragma unroll
            for (int rt = 0; rt < 8; ++rt) {
                const int m = rt * 16 + l15;
                const int g = ktl * 4 + q;      // granule 0..15
                a[rt] = *(const bf16x8*)(XS + m * 256 + ((g ^ swz(m)) << 4));
            }
#pragma unroll
            for (int c = 0; c < 4; ++c) {
                const int nt = wave * 4 + c;
                const bf16x8 b = w1[(nt * 8 + half * 4 + ktl) * 64 + lane];
#pragma unroll
                for (int rt = 0; rt < 8; ++rt)
                    acc[rt][c] = __builtin_amdgcn_mfma_f32_16x16x32_bf16(a[rt], b, acc[rt][c], 0, 0, 0);
            }
        }
    }
    // ---- epilogue: relu + bias -> HX (bf16, swizzled). HX first touch here.
#pragma unroll
    for (int c = 0; c < 4; ++c) {
        const int n = (wave * 4 + c) * 16 + l15;
        const float bias = b1[n];
        const int cg = n >> 3;
        const int nl = n & 7;
#pragma unroll
        for (int rt = 0; rt < 8; ++rt)
#pragma unroll
            for (int r = 0; r < 4; ++r) {
                const int m = rt * 16 + q * 4 + r;
                float v = acc[rt][c][r] + bias;
                v = fmaxf(v, 0.f);
                *(short*)(HX + m * 1024 + ((cg ^ swz(m)) << 4) + nl * 2) = f2bf(v);
            }
    }
    __syncthreads();

    // =============== Phase 2: h2 = relu(h1 @ W2 + b2), K=512 ===============
#pragma unroll
    for (int rt = 0; rt < 8; ++rt)
#pragma unroll
        for (int c = 0; c < 4; ++c) acc[rt][c] = zero4;

    const bf16x8* w2 = (const bf16x8*)wp + (W2P_OFF >> 3);
    for (int kt = 0; kt < 16; ++kt) {
        bf16x8 a[8];
#pragma unroll
        for (int rt = 0; rt < 8; ++rt) {
            const int m = rt * 16 + l15;
            const int g = kt * 4 + q;           // granule 0..63
            a[rt] = *(const bf16x8*)(HX + m * 1024 + ((g ^ swz(m)) << 4));
        }
#pragma unroll
        for (int c = 0; c < 4; ++c) {
            const int nt = wave * 4 + c;
            const bf16x8 b = w2[(nt * 16 + kt) * 64 + lane];
#pragma unroll
            for (int rt = 0; rt < 8; ++rt)
                acc[rt][c] = __builtin_amdgcn_mfma_f32_16x16x32_bf16(a[rt], b, acc[rt][c], 0, 0, 0);
        }
    }
    __syncthreads();                            // all h1 reads done
    // ---- epilogue: relu + bias -> HX in place (h2 overwrites h1)
#pragma unroll
    for (int c = 0; c < 4; ++c) {
        const int n = (wave * 4 + c) * 16 + l15;
        const float bias = b2[n];
        const int cg = n >> 3;
        const int nl = n & 7;
#pragma unroll
        for (int rt = 0; rt < 8; ++rt)
#pragma unroll
            for (int r = 0; r < 4; ++r) {
                const int m = rt * 16 + q * 4 + r;
                float v = acc[rt][c][r] + bias;
                v = fmaxf(v, 0.f);
                *(short*)(HX + m * 1024 + ((cg ^ swz(m)) << 4) + nl * 2) = f2bf(v);
            }
    }
    __syncthreads();

    // =============== Phase 3: y = silu(h2 @ W3 + b3), K=512 ================
    f32x4 acc3[8];
#pragma unroll
    for (int rt = 0; rt < 8; ++rt) acc3[rt] = zero4;

    const bf16x8* w3 = (const bf16x8*)wp + (W3P_OFF >> 3);
    for (int kt = 0; kt < 16; ++kt) {
        bf16x8 a[8];
#pragma unroll
        for (int rt = 0; rt < 8; ++rt) {
            const int m = rt * 16 + l15;
            const int g = kt * 4 + q;
            a[rt] = *(const bf16x8*)(HX + m * 1024 + ((g ^ swz(m)) << 4));
        }
        const bf16x8 b = w3[(wave * 16 + kt) * 64 + lane];
#pragma unroll
        for (int rt = 0; rt < 8; ++rt)
            acc3[rt] = __builtin_amdgcn_mfma_f32_16x16x32_bf16(a[rt], b, acc3[rt], 0, 0, 0);
    }
    __syncthreads();                            // all h2 reads done
    // ---- epilogue: silu -> y (f32, stride 132 floats) into HX; gs into XS
    {
        float* yl = (float*)HX;
        const int n = wave * 16 + l15;
        const float bias = b3[n];
#pragma unroll
        for (int rt = 0; rt < 8; ++rt)
#pragma unroll
            for (int r = 0; r < 4; ++r) {
                const int m = rt * 16 + q * 4 + r;
                const float yv = acc3[rt][r] + bias;
                yl[m * 132 + n] = yv / (1.f + __expf(-yv));   // SiLU
            }
        int* gs = (int*)XS;
        if (t < BM) gs[t] = (t < valid) ? gidx[rowBase + t] : 0;
    }
    __syncthreads();

    // =============== Phase 4: segmented reduction + global atomics =========
    {
        const int col = t & 127;
        const int r0  = (t >> 7) * 32;          // 4 row chunks of 32
        const int r1  = min(r0 + 32, valid);
        if (r0 < valid) {
            const int*   gs = (const int*)XS;
            const float* yl = (const float*)HX;
            int   gprev = gs[r0];
            float s     = 0.f;
            for (int r = r0; r < r1; ++r) {
                const int g = gs[r];
                if (g != gprev) {
                    atomicAdd(out + gprev * N_OUT + col, s);
                    s = 0.f;
                    gprev = g;
                }
                s += yl[r * 132 + col];
            }
            atomicAdd(out + gprev * N_OUT + col, s);
        }
    }
}

extern "C" void kernel_launch(void* const* d_in, const int* in_sizes, int n_in,
                              void* d_out, int out_size, void* d_ws, size_t ws_size,
                              hipStream_t stream) {
    const float* X    = (const float*)d_in[0];
    const int*   gidx = (const int*)  d_in[1];
    const float* W1   = (const float*)d_in[2];
    const float* b1   = (const float*)d_in[3];
    const float* W2   = (const float*)d_in[4];
    const float* b2   = (const float*)d_in[5];
    const float* W3   = (const float*)d_in[6];
    const float* b3   = (const float*)d_in[7];
    float* out = (float*)d_out;
    short* wp  = (short*)d_ws;

    // opt-in to >64 KiB dynamic LDS (idempotent, host-side, graph-safe)
    hipFuncSetAttribute((const void*)fused_mlp,
                        hipFuncAttributeMaxDynamicSharedMemorySize, LDS_BYTES);

    hipMemsetAsync(d_out, 0, sizeof(float) * N_GRAPHS * N_OUT, stream);

    prepack_weights<<<PREPACK_THREADS / 256, 256, 0, stream>>>(W1, W2, W3, wp);

    fused_mlp<<<N_BLOCKS, 512, LDS_BYTES, stream>>>(X, gidx, wp, b1, b2, b3, out);
}